// Round 1
// baseline (292.202 us; speedup 1.0000x reference)
//
#include <hip/hip_runtime.h>

#define KS 11
#define PAD 5
#define TDIM 32
#define LROWS (TDIM + 2 * PAD)   // 42
#define NTHREADS 256

__device__ __forceinline__ void gauss_weights(float kw[KS]) {
    float s = 0.f;
#pragma unroll
    for (int i = 0; i < KS; ++i) {
        float x = (float)(i - PAD);
        kw[i] = expf(-x * x / (2.f * 1.5f * 1.5f));
        s += kw[i];
    }
#pragma unroll
    for (int i = 0; i < KS; ++i) kw[i] /= s;
}

// One block = one 32x32 output tile of one (b,c) image at this level.
// Computes SSIM/CS partial sums (atomicAdd into accCS/accSSIM[b]) and the
// 2x2-avg-pooled next-level images (if p1/p2 non-null).
__global__ __launch_bounds__(NTHREADS) void ssim_pool_kernel(
    const float* __restrict__ x1, const float* __restrict__ x2,
    float* __restrict__ p1, float* __restrict__ p2,
    float* __restrict__ accCS, float* __restrict__ accSSIM,
    int H, int W, int tilesX, int tilesY) {

    __shared__ float s1[LROWS][LROWS + 2];
    __shared__ float s2[LROWS][LROWS + 2];
    __shared__ float hb[5][LROWS][TDIM];
    __shared__ float red[8];

    const int t = threadIdx.x;
    const int tilesPerImg = tilesX * tilesY;
    const int img = blockIdx.x / tilesPerImg;
    const int rem = blockIdx.x % tilesPerImg;
    const int tyv = rem / tilesX;
    const int txv = rem % tilesX;
    const int b = img / 3;
    const int gy0 = tyv * TDIM;
    const int gx0 = txv * TDIM;

    const float* __restrict__ i1 = x1 + (size_t)img * H * W;
    const float* __restrict__ i2 = x2 + (size_t)img * H * W;

    // ---- load tile + halo (zero padding outside the image) ----
    for (int idx = t; idx < LROWS * LROWS; idx += NTHREADS) {
        int r = idx / LROWS;
        int c = idx - r * LROWS;
        int gy = gy0 + r - PAD;
        int gx = gx0 + c - PAD;
        bool in = (gy >= 0) & (gy < H) & (gx >= 0) & (gx < W);
        size_t off = (size_t)gy * W + gx;
        s1[r][c] = in ? i1[off] : 0.f;
        s2[r][c] = in ? i2[off] : 0.f;
    }
    __syncthreads();

    float kw[KS];
    gauss_weights(kw);

    // ---- fused 2x2 avg-pool for the next level (reads LDS interior) ----
    if (p1 != nullptr) {
        int py = t >> 4, px = t & 15;         // 16x16 pooled outputs per tile
        int r = 2 * py + PAD, c = 2 * px + PAD;
        float v1 = 0.25f * (s1[r][c] + s1[r][c + 1] + s1[r + 1][c] + s1[r + 1][c + 1]);
        float v2 = 0.25f * (s2[r][c] + s2[r][c + 1] + s2[r + 1][c] + s2[r + 1][c + 1]);
        int Wp = W >> 1;
        int Hp = H >> 1;
        size_t off = (size_t)img * Hp * Wp + (size_t)((gy0 >> 1) + py) * Wp + ((gx0 >> 1) + px);
        p1[off] = v1;
        p2[off] = v2;
    }

    // ---- horizontal 11-tap pass for the 5 moments ----
    for (int idx = t; idx < LROWS * TDIM; idx += NTHREADS) {
        int r = idx >> 5;
        int c = idx & 31;
        float a1 = 0.f, a2 = 0.f, a11 = 0.f, a22 = 0.f, a12 = 0.f;
#pragma unroll
        for (int i = 0; i < KS; ++i) {
            float w = kw[i];
            float v1 = s1[r][c + i];
            float v2 = s2[r][c + i];
            a1 += w * v1;
            a2 += w * v2;
            a11 += w * v1 * v1;
            a22 += w * v2 * v2;
            a12 += w * v1 * v2;
        }
        hb[0][r][c] = a1;
        hb[1][r][c] = a2;
        hb[2][r][c] = a11;
        hb[3][r][c] = a22;
        hb[4][r][c] = a12;
    }
    __syncthreads();

    // ---- vertical 11-tap pass + SSIM/CS epilogue ----
    const float C1 = 0.0001f;  // (0.01*1)^2
    const float C2 = 0.0009f;  // (0.03*1)^2
    float ssim_s = 0.f, cs_s = 0.f;
    for (int idx = t; idx < TDIM * TDIM; idx += NTHREADS) {
        int r = idx >> 5;
        int c = idx & 31;
        float m1 = 0.f, m2 = 0.f, m11 = 0.f, m22 = 0.f, m12 = 0.f;
#pragma unroll
        for (int j = 0; j < KS; ++j) {
            float w = kw[j];
            m1 += w * hb[0][r + j][c];
            m2 += w * hb[1][r + j][c];
            m11 += w * hb[2][r + j][c];
            m22 += w * hb[3][r + j][c];
            m12 += w * hb[4][r + j][c];
        }
        float mu11 = m1 * m1, mu22 = m2 * m2, mu12 = m1 * m2;
        float sg1 = m11 - mu11, sg2 = m22 - mu22, sg12 = m12 - mu12;
        float cs = (2.f * sg12 + C2) / (sg1 + sg2 + C2);
        float ss = (2.f * mu12 + C1) / (mu11 + mu22 + C1) * cs;
        ssim_s += ss;
        cs_s += cs;
    }

    // ---- block reduction -> atomicAdd per (level, b) ----
#pragma unroll
    for (int o = 32; o > 0; o >>= 1) {
        ssim_s += __shfl_down(ssim_s, o);
        cs_s += __shfl_down(cs_s, o);
    }
    int wid = t >> 6, lane = t & 63;
    if (lane == 0) {
        red[wid] = ssim_s;
        red[4 + wid] = cs_s;
    }
    __syncthreads();
    if (t == 0) {
        float a = red[0] + red[1] + red[2] + red[3];
        float c = red[4] + red[5] + red[6] + red[7];
        atomicAdd(&accSSIM[b], a);
        atomicAdd(&accCS[b], c);
    }
}

// acc layout: cs sums at acc[l*16+b], ssim sums at acc[80 + l*16+b]
__global__ void finalize_kernel(const float* __restrict__ acc, float* __restrict__ out) {
    __shared__ float vals[16];
    int t = threadIdx.x;
    if (t < 16) {
        const float w[5] = {0.0448f, 0.2856f, 0.3001f, 0.2363f, 0.1333f};
        float v = 1.f;
#pragma unroll
        for (int l = 0; l < 5; ++l) {
            int Hl = 512 >> l;
            float denom = 3.f * (float)Hl * (float)Hl;
            float m = (l < 4) ? acc[l * 16 + t] : acc[80 + l * 16 + t];
            m = m / denom;
            m = fmaxf(m, 0.f);
            v *= powf(m, w[l]);
        }
        vals[t] = v;
    }
    __syncthreads();
    if (t == 0) {
        float s = 0.f;
        for (int i = 0; i < 16; ++i) s += vals[i];
        out[0] = s / 16.f;
    }
}

extern "C" void kernel_launch(void* const* d_in, const int* in_sizes, int n_in,
                              void* d_out, int out_size, void* d_ws, size_t ws_size,
                              hipStream_t stream) {
    const float* img1 = (const float*)d_in[0];
    const float* img2 = (const float*)d_in[1];
    float* out = (float*)d_out;
    float* ws = (float*)d_ws;

    // ws layout (floats): [0,256) accumulators; then x1 pyramid L1..L4; then x2.
    float* acc = ws;
    size_t off = 256;
    float* x1l[5];
    float* x2l[5];
    x1l[0] = (float*)img1;
    x2l[0] = (float*)img2;
    size_t lvlElems[5];
    for (int l = 0; l < 5; ++l) {
        int Hl = 512 >> l;
        lvlElems[l] = (size_t)48 * Hl * Hl;
    }
    for (int l = 1; l < 5; ++l) { x1l[l] = ws + off; off += lvlElems[l]; }
    for (int l = 1; l < 5; ++l) { x2l[l] = ws + off; off += lvlElems[l]; }

    hipMemsetAsync(acc, 0, 256 * sizeof(float), stream);

    for (int l = 0; l < 5; ++l) {
        int Hl = 512 >> l;
        int tiles = Hl / TDIM;
        int nblk = 48 * tiles * tiles;
        float* p1 = (l < 4) ? x1l[l + 1] : nullptr;
        float* p2 = (l < 4) ? x2l[l + 1] : nullptr;
        ssim_pool_kernel<<<nblk, NTHREADS, 0, stream>>>(
            x1l[l], x2l[l], p1, p2,
            acc + l * 16, acc + 80 + l * 16,
            Hl, Hl, tiles, tiles);
    }
    finalize_kernel<<<1, 64, 0, stream>>>(acc, out);
}

// Round 2
// 284.144 us; speedup vs baseline: 1.0284x; 1.0284x over previous
//
#include <hip/hip_runtime.h>

#define KS 11
#define PAD 5
#define TDIM 32
#define LROWS 42          // TDIM + 2*PAD
#define SPITCH 44         // LDS pitch for s1/s2 (floats), %4==0 for b128
#define TP 44             // LDS pitch for transposed intermediate
#define NTHREADS 256

// Gaussian(sigma=1.5, 11 taps), normalized; computed in double, matches fp32 ref
__device__ const float KW[KS] = {
    0.00102838f, 0.00759878f, 0.03600077f, 0.10936069f, 0.21300553f,
    0.26601172f,
    0.21300553f, 0.10936069f, 0.03600077f, 0.00759878f, 0.00102838f};

// One block = one 32x32 output tile of one (b,c) image at this level.
__global__ __launch_bounds__(NTHREADS) void ssim_pool_kernel(
    const float* __restrict__ x1, const float* __restrict__ x2,
    float* __restrict__ p1, float* __restrict__ p2,
    float* __restrict__ accCS, float* __restrict__ accSSIM,
    int H, int W, int tilesX) {

    __shared__ __align__(16) float s1[LROWS][SPITCH];
    __shared__ __align__(16) float s2[LROWS][SPITCH];
    __shared__ __align__(16) float hbt[5][TDIM][TP];  // [moment][col][row]
    __shared__ float red[8];

    const int t = threadIdx.x;
    const int tilesPerImg = tilesX * tilesX;
    const int img = blockIdx.x / tilesPerImg;
    const int rem = blockIdx.x % tilesPerImg;
    const int tyv = rem / tilesX;
    const int txv = rem % tilesX;
    const int b = img / 3;
    const int gy0 = tyv * TDIM;
    const int gx0 = txv * TDIM;

    const float* __restrict__ i1 = x1 + (size_t)img * H * W;
    const float* __restrict__ i2 = x2 + (size_t)img * H * W;

    // ---- load tile + halo (zero padding outside the image) ----
    for (int idx = t; idx < LROWS * LROWS; idx += NTHREADS) {
        int r = idx / LROWS;
        int c = idx - r * LROWS;
        int gy = gy0 + r - PAD;
        int gx = gx0 + c - PAD;
        bool in = (gy >= 0) & (gy < H) & (gx >= 0) & (gx < W);
        size_t off = (size_t)gy * W + gx;
        s1[r][c] = in ? i1[off] : 0.f;
        s2[r][c] = in ? i2[off] : 0.f;
    }
    __syncthreads();

    // ---- fused 2x2 avg-pool for the next level (raw inputs, LDS interior) ----
    if (p1 != nullptr) {
        int py = t >> 4, px = t & 15;  // 16x16 pooled outputs per tile
        int r = 2 * py + PAD, c = 2 * px + PAD;
        float v1 = 0.25f * (s1[r][c] + s1[r][c + 1] + s1[r + 1][c] + s1[r + 1][c + 1]);
        float v2 = 0.25f * (s2[r][c] + s2[r][c + 1] + s2[r + 1][c] + s2[r + 1][c + 1]);
        int Wp = W >> 1;
        int Hp = H >> 1;
        size_t off = (size_t)img * Hp * Wp + (size_t)((gy0 >> 1) + py) * Wp + ((gx0 >> 1) + px);
        p1[off] = v1;
        p2[off] = v2;
    }

    // ---- horizontal 11-tap pass, vectorized: 4 outputs/task via b128 reads ----
    // tasks: 8 colgroups x 42 rows; output -> transposed hbt[m][col][row]
    for (int idx = t; idx < 8 * LROWS; idx += NTHREADS) {
        int cg = idx / LROWS;
        int r = idx - cg * LROWS;
        int c0 = cg << 2;

        float in1[16], in2[16];
        *(float4*)&in1[0]  = *(const float4*)&s1[r][c0];
        *(float4*)&in1[4]  = *(const float4*)&s1[r][c0 + 4];
        *(float4*)&in1[8]  = *(const float4*)&s1[r][c0 + 8];
        *(float4*)&in1[12] = *(const float4*)&s1[r][c0 + 12];
        *(float4*)&in2[0]  = *(const float4*)&s2[r][c0];
        *(float4*)&in2[4]  = *(const float4*)&s2[r][c0 + 4];
        *(float4*)&in2[8]  = *(const float4*)&s2[r][c0 + 8];
        *(float4*)&in2[12] = *(const float4*)&s2[r][c0 + 12];

        float acc[5][4];
#pragma unroll
        for (int m = 0; m < 5; ++m)
#pragma unroll
            for (int k = 0; k < 4; ++k) acc[m][k] = 0.f;

#pragma unroll
        for (int i = 0; i < 14; ++i) {
            float v1 = in1[i], v2 = in2[i];
            float q11 = v1 * v1, q22 = v2 * v2, q12 = v1 * v2;
#pragma unroll
            for (int k = 0; k < 4; ++k) {
                int j = i - k;
                if (j >= 0 && j <= 10) {
                    float w = KW[j];
                    acc[0][k] += w * v1;
                    acc[1][k] += w * v2;
                    acc[2][k] += w * q11;
                    acc[3][k] += w * q22;
                    acc[4][k] += w * q12;
                }
            }
        }
#pragma unroll
        for (int m = 0; m < 5; ++m)
#pragma unroll
            for (int k = 0; k < 4; ++k) hbt[m][c0 + k][r] = acc[m][k];
    }
    __syncthreads();

    // ---- vertical 11-tap pass (contiguous in transposed layout) + epilogue ----
    const float C1 = 0.0001f;
    const float C2 = 0.0009f;
    float ssim_s = 0.f, cs_s = 0.f;
    {
        int c = t & 31;    // output column
        int rg = t >> 5;   // row group: rows 4*rg .. 4*rg+3
        int r0 = rg << 2;

        float acc[5][4];
#pragma unroll
        for (int m = 0; m < 5; ++m) {
            float in[16];
            *(float4*)&in[0]  = *(const float4*)&hbt[m][c][r0];
            *(float4*)&in[4]  = *(const float4*)&hbt[m][c][r0 + 4];
            *(float4*)&in[8]  = *(const float4*)&hbt[m][c][r0 + 8];
            *(float4*)&in[12] = *(const float4*)&hbt[m][c][r0 + 12];
#pragma unroll
            for (int k = 0; k < 4; ++k) acc[m][k] = 0.f;
#pragma unroll
            for (int i = 0; i < 14; ++i) {
#pragma unroll
                for (int k = 0; k < 4; ++k) {
                    int j = i - k;
                    if (j >= 0 && j <= 10) acc[m][k] += KW[j] * in[i];
                }
            }
        }
#pragma unroll
        for (int k = 0; k < 4; ++k) {
            float m1 = acc[0][k], m2 = acc[1][k];
            float mu11 = m1 * m1, mu22 = m2 * m2, mu12 = m1 * m2;
            float sg1 = acc[2][k] - mu11, sg2 = acc[3][k] - mu22, sg12 = acc[4][k] - mu12;
            float cs = (2.f * sg12 + C2) / (sg1 + sg2 + C2);
            float ss = (2.f * mu12 + C1) * cs / (mu11 + mu22 + C1);
            cs_s += cs;
            ssim_s += ss;
        }
    }

    // ---- block reduction -> atomicAdd per (level, b) ----
#pragma unroll
    for (int o = 32; o > 0; o >>= 1) {
        ssim_s += __shfl_down(ssim_s, o);
        cs_s += __shfl_down(cs_s, o);
    }
    int wid = t >> 6, lane = t & 63;
    if (lane == 0) {
        red[wid] = ssim_s;
        red[4 + wid] = cs_s;
    }
    __syncthreads();
    if (t == 0) {
        float a = red[0] + red[1] + red[2] + red[3];
        float c = red[4] + red[5] + red[6] + red[7];
        atomicAdd(&accSSIM[b], a);
        atomicAdd(&accCS[b], c);
    }
}

// acc layout: cs sums at acc[l*16+b], ssim sums at acc[80 + l*16+b]
__global__ void finalize_kernel(const float* __restrict__ acc, float* __restrict__ out) {
    __shared__ float vals[16];
    int t = threadIdx.x;
    if (t < 16) {
        const float w[5] = {0.0448f, 0.2856f, 0.3001f, 0.2363f, 0.1333f};
        float v = 1.f;
#pragma unroll
        for (int l = 0; l < 5; ++l) {
            int Hl = 512 >> l;
            float denom = 3.f * (float)Hl * (float)Hl;
            float m = (l < 4) ? acc[l * 16 + t] : acc[80 + l * 16 + t];
            m = m / denom;
            m = fmaxf(m, 0.f);
            v *= powf(m, w[l]);
        }
        vals[t] = v;
    }
    __syncthreads();
    if (t == 0) {
        float s = 0.f;
        for (int i = 0; i < 16; ++i) s += vals[i];
        out[0] = s / 16.f;
    }
}

extern "C" void kernel_launch(void* const* d_in, const int* in_sizes, int n_in,
                              void* d_out, int out_size, void* d_ws, size_t ws_size,
                              hipStream_t stream) {
    const float* img1 = (const float*)d_in[0];
    const float* img2 = (const float*)d_in[1];
    float* out = (float*)d_out;
    float* ws = (float*)d_ws;

    float* acc = ws;
    size_t off = 256;
    float* x1l[5];
    float* x2l[5];
    x1l[0] = (float*)img1;
    x2l[0] = (float*)img2;
    size_t lvlElems[5];
    for (int l = 0; l < 5; ++l) {
        int Hl = 512 >> l;
        lvlElems[l] = (size_t)48 * Hl * Hl;
    }
    for (int l = 1; l < 5; ++l) { x1l[l] = ws + off; off += lvlElems[l]; }
    for (int l = 1; l < 5; ++l) { x2l[l] = ws + off; off += lvlElems[l]; }

    hipMemsetAsync(acc, 0, 256 * sizeof(float), stream);

    for (int l = 0; l < 5; ++l) {
        int Hl = 512 >> l;
        int tiles = Hl / TDIM;
        int nblk = 48 * tiles * tiles;
        float* p1 = (l < 4) ? x1l[l + 1] : nullptr;
        float* p2 = (l < 4) ? x2l[l + 1] : nullptr;
        ssim_pool_kernel<<<nblk, NTHREADS, 0, stream>>>(
            x1l[l], x2l[l], p1, p2,
            acc + l * 16, acc + 80 + l * 16,
            Hl, Hl, tiles);
    }
    finalize_kernel<<<1, 64, 0, stream>>>(acc, out);
}

// Round 6
// 259.541 us; speedup vs baseline: 1.1258x; 1.0948x over previous
//
#include <hip/hip_runtime.h>

#define KS 11
#define PAD 5
#define TDIM 32
#define HROWS 42          // TDIM + 2*PAD H-filtered rows
#define HPITCH 33         // pitch: (r + 4*cg + k) mod 32 all-distinct -> conflict-free
#define NTHREADS 256

// One block = one 32x32 output tile of one (b,c) image at this level.
__global__ __launch_bounds__(NTHREADS, 5) void ssim_pool_kernel(
    const float* __restrict__ x1, const float* __restrict__ x2,
    float* __restrict__ p1, float* __restrict__ p2,
    float* __restrict__ accCS, float* __restrict__ accSSIM,
    int H, int W, int tilesX) {

    __shared__ __align__(16) float hbt[5 * HROWS * HPITCH];  // 27720 B
    __shared__ float red[8];

    const float KW[KS] = {
        0.00102838f, 0.00759878f, 0.03600077f, 0.10936069f, 0.21300553f,
        0.26601172f,
        0.21300553f, 0.10936069f, 0.03600077f, 0.00759878f, 0.00102838f};

    const int t = threadIdx.x;
    const int tilesPerImg = tilesX * tilesX;
    const int img = blockIdx.x / tilesPerImg;
    const int rem = blockIdx.x % tilesPerImg;
    const int tyv = rem / tilesX;
    const int txv = rem % tilesX;
    const int b = img / 3;
    const int gy0 = tyv * TDIM;
    const int gx0 = txv * TDIM;

    const float* __restrict__ i1 = x1 + (size_t)img * H * W;
    const float* __restrict__ i2 = x2 + (size_t)img * H * W;

    // ---- fused 2x2 avg-pool for the next level (raw global reads, interior) ----
    if (p1 != nullptr) {
        int py = t >> 4, px = t & 15;  // 16x16 pooled outputs per tile
        int rr = gy0 + 2 * py;
        int cc = gx0 + 2 * px;
        float2 a1 = *(const float2*)&i1[(size_t)rr * W + cc];
        float2 b1 = *(const float2*)&i1[(size_t)(rr + 1) * W + cc];
        float2 a2 = *(const float2*)&i2[(size_t)rr * W + cc];
        float2 b2 = *(const float2*)&i2[(size_t)(rr + 1) * W + cc];
        float v1 = 0.25f * (a1.x + a1.y + b1.x + b1.y);
        float v2 = 0.25f * (a2.x + a2.y + b2.x + b2.y);
        int Wp = W >> 1, Hp = H >> 1;
        size_t off = (size_t)img * Hp * Wp + (size_t)((gy0 >> 1) + py) * Wp + ((gx0 >> 1) + px);
        p1[off] = v1;
        p2[off] = v2;
    }

    // ---- H-pass: 8 colgroups x 42 rows; windows read straight from global ----
    for (int idx = t; idx < 8 * HROWS; idx += NTHREADS) {
        int cg = idx & 7;
        int r = idx >> 3;
        int gy = gy0 + r - PAD;
        int gxlo = gx0 + (cg << 2) - 8;   // 16B-aligned when in-bounds

        float L1v[20], L2v[20];
#pragma unroll
        for (int e = 0; e < 20; ++e) { L1v[e] = 0.f; L2v[e] = 0.f; }

        if (gy >= 0 && gy < H) {
            const float* __restrict__ r1 = i1 + (size_t)gy * W;
            const float* __restrict__ r2 = i2 + (size_t)gy * W;
            if (gxlo >= 0 && gxlo + 20 <= W) {
#pragma unroll
                for (int q = 0; q < 5; ++q) {
                    *(float4*)&L1v[4 * q] = *(const float4*)&r1[gxlo + 4 * q];
                    *(float4*)&L2v[4 * q] = *(const float4*)&r2[gxlo + 4 * q];
                }
            } else {
#pragma unroll
                for (int e = 0; e < 20; ++e) {
                    int col = gxlo + e;
                    bool ok = (col >= 0) & (col < W);
                    L1v[e] = ok ? r1[ok ? col : 0] : 0.f;
                    L2v[e] = ok ? r2[ok ? col : 0] : 0.f;
                }
            }
        }

        float acc[5][4];
#pragma unroll
        for (int m = 0; m < 5; ++m)
#pragma unroll
            for (int k = 0; k < 4; ++k) acc[m][k] = 0.f;

        // window position i (0..13) = loaded element i+3
#pragma unroll
        for (int i = 0; i < 14; ++i) {
            float v1 = L1v[i + 3], v2 = L2v[i + 3];
            float q11 = v1 * v1, q22 = v2 * v2, q12 = v1 * v2;
#pragma unroll
            for (int k = 0; k < 4; ++k) {
                int j = i - k;
                if (j >= 0 && j <= 10) {
                    float w = KW[j];
                    acc[0][k] += w * v1;
                    acc[1][k] += w * v2;
                    acc[2][k] += w * q11;
                    acc[3][k] += w * q22;
                    acc[4][k] += w * q12;
                }
            }
        }
        int c0 = cg << 2;
#pragma unroll
        for (int m = 0; m < 5; ++m) {
            float* hb = &hbt[(m * HROWS + r) * HPITCH + c0];
#pragma unroll
            for (int k = 0; k < 4; ++k) hb[k] = acc[m][k];
        }
    }
    __syncthreads();

    // ---- V-pass: thread = (col, 4 rows); scalar conflict-free LDS reads ----
    const float C1 = 0.0001f;
    const float C2 = 0.0009f;
    float ssim_s = 0.f, cs_s = 0.f;
    {
        int c = t & 31;
        int r0 = (t >> 5) << 2;

        float accv[5][4];
#pragma unroll
        for (int m = 0; m < 5; ++m) {
            float win[14];
#pragma unroll
            for (int i = 0; i < 14; ++i)
                win[i] = hbt[(m * HROWS + r0 + i) * HPITCH + c];
#pragma unroll
            for (int k = 0; k < 4; ++k) accv[m][k] = 0.f;
#pragma unroll
            for (int i = 0; i < 14; ++i) {
#pragma unroll
                for (int k = 0; k < 4; ++k) {
                    int j = i - k;
                    if (j >= 0 && j <= 10) accv[m][k] += KW[j] * win[i];
                }
            }
        }
#pragma unroll
        for (int k = 0; k < 4; ++k) {
            float m1 = accv[0][k], m2 = accv[1][k];
            float mu11 = m1 * m1, mu22 = m2 * m2, mu12 = m1 * m2;
            float sg1 = accv[2][k] - mu11, sg2 = accv[3][k] - mu22, sg12 = accv[4][k] - mu12;
            float cs = (2.f * sg12 + C2) / (sg1 + sg2 + C2);
            float ss = (2.f * mu12 + C1) * cs / (mu11 + mu22 + C1);
            cs_s += cs;
            ssim_s += ss;
        }
    }

    // ---- block reduction -> atomicAdd per (level, b) ----
#pragma unroll
    for (int o = 32; o > 0; o >>= 1) {
        ssim_s += __shfl_down(ssim_s, o);
        cs_s += __shfl_down(cs_s, o);
    }
    int wid = t >> 6, lane = t & 63;
    if (lane == 0) {
        red[wid] = ssim_s;
        red[4 + wid] = cs_s;
    }
    __syncthreads();
    if (t == 0) {
        float a = red[0] + red[1] + red[2] + red[3];
        float c = red[4] + red[5] + red[6] + red[7];
        atomicAdd(&accSSIM[b], a);
        atomicAdd(&accCS[b], c);
    }
}

// acc layout: cs sums at acc[l*16+b], ssim sums at acc[80 + l*16+b]
__global__ void finalize_kernel(const float* __restrict__ acc, float* __restrict__ out) {
    __shared__ float vals[16];
    int t = threadIdx.x;
    if (t < 16) {
        const float w[5] = {0.0448f, 0.2856f, 0.3001f, 0.2363f, 0.1333f};
        float v = 1.f;
#pragma unroll
        for (int l = 0; l < 5; ++l) {
            int Hl = 512 >> l;
            float denom = 3.f * (float)Hl * (float)Hl;
            float m = (l < 4) ? acc[l * 16 + t] : acc[80 + l * 16 + t];
            m = m / denom;
            m = fmaxf(m, 0.f);
            v *= powf(m, w[l]);
        }
        vals[t] = v;
    }
    __syncthreads();
    if (t == 0) {
        float s = 0.f;
        for (int i = 0; i < 16; ++i) s += vals[i];
        out[0] = s / 16.f;
    }
}

extern "C" void kernel_launch(void* const* d_in, const int* in_sizes, int n_in,
                              void* d_out, int out_size, void* d_ws, size_t ws_size,
                              hipStream_t stream) {
    const float* img1 = (const float*)d_in[0];
    const float* img2 = (const float*)d_in[1];
    float* out = (float*)d_out;
    float* ws = (float*)d_ws;

    float* acc = ws;
    size_t off = 256;
    float* x1l[5];
    float* x2l[5];
    x1l[0] = (float*)img1;
    x2l[0] = (float*)img2;
    size_t lvlElems[5];
    for (int l = 0; l < 5; ++l) {
        int Hl = 512 >> l;
        lvlElems[l] = (size_t)48 * Hl * Hl;
    }
    for (int l = 1; l < 5; ++l) { x1l[l] = ws + off; off += lvlElems[l]; }
    for (int l = 1; l < 5; ++l) { x2l[l] = ws + off; off += lvlElems[l]; }

    hipMemsetAsync(acc, 0, 256 * sizeof(float), stream);

    for (int l = 0; l < 5; ++l) {
        int Hl = 512 >> l;
        int tiles = Hl / TDIM;
        int nblk = 48 * tiles * tiles;
        float* p1 = (l < 4) ? x1l[l + 1] : nullptr;
        float* p2 = (l < 4) ? x2l[l + 1] : nullptr;
        ssim_pool_kernel<<<nblk, NTHREADS, 0, stream>>>(
            x1l[l], x2l[l], p1, p2,
            acc + l * 16, acc + 80 + l * 16,
            Hl, Hl, tiles);
    }
    finalize_kernel<<<1, 64, 0, stream>>>(acc, out);
}